// Round 2
// baseline (15470.248 us; speedup 1.0000x reference)
//
#include <hip/hip_runtime.h>
#include <hip/hip_bf16.h>
#include <stdint.h>

typedef __bf16  bf16x8 __attribute__((ext_vector_type(8)));
typedef float   f32x16 __attribute__((ext_vector_type(16)));

#define NB   64
#define NT   1024
#define ND   256
#define NH   512
#define NWGD 32

// LDS layout (bytes)
#define LDS_WFR   0                        // 48*2*64*8 bf16 = 98304
#define LDS_RED   98304                    // 4*64*17 f32   = 17408
#define LDS_HOUT  (98304+17408)            // 64*16 bf16    = 2048
#define LDS_BIAS  (98304+17408+2048)       // 64 f32        = 256
#define LDS_TOTAL (98304+17408+2048+256)   // 118016 -> 1 WG/CU

static __device__ __forceinline__ unsigned long long agent_load_u64(const void* p) {
  return __hip_atomic_load((const unsigned long long*)p, __ATOMIC_RELAXED,
                           __HIP_MEMORY_SCOPE_AGENT);
}
static __device__ __forceinline__ void agent_store_u64(void* p, unsigned long long v) {
  __hip_atomic_store((unsigned long long*)p, v, __ATOMIC_RELAXED,
                     __HIP_MEMORY_SCOPE_AGENT);
}
static __device__ __forceinline__ float fast_sigmoid(float v) {
  return __builtin_amdgcn_rcpf(1.0f + __expf(-v));
}
static __device__ __forceinline__ float fast_tanh(float v) {
  return 1.0f - 2.0f * __builtin_amdgcn_rcpf(1.0f + __expf(2.0f * v));
}

// Persistent bidirectional LSTM. 64 WGs: dir = bid>>5, jsl = bid&31 (16 hidden
// units -> 64 gate cols, gate-interleaved n=4u+g). Per step per WG:
// G^T[64][64b] = Wslice^T[64][768] @ act^T[768][64], mfma_f32_32x32x16_bf16.
// Waves (ni=batch-half, kh=K-half). K split: phase A (x, flag-independent):
// kh0 kk0..7, kh1 kk8..15; phase C (h, after flag poll): kh0 kk16..31,
// kh1 kk32..47. Cross-step sync: per-WG flag words + wave-parallel poll
// (no contended RMW). Wave kh finalizes regs r in [8kh,8kh+8) after a
// symmetric half-exchange through LDS.
__global__ __launch_bounds__(256, 1) void bilstm_persist(
    const float* __restrict__ x,
    const float* __restrict__ Wf, const float* __restrict__ bf_,
    const float* __restrict__ Wb, const float* __restrict__ bb_,
    __hip_bfloat16* __restrict__ hbuf, unsigned int* __restrict__ flags)
{
  extern __shared__ char smem[];
  __bf16*         wfr   = (__bf16*)(smem + LDS_WFR);
  float*          red   = (float*) (smem + LDS_RED);
  __hip_bfloat16* hout  = (__hip_bfloat16*)(smem + LDS_HOUT);
  float*          biasl = (float*) (smem + LDS_BIAS);

  const int tid = threadIdx.x;
  const int bid = blockIdx.x;
  const int dir = bid >> 5;
  const int jsl = bid & 31;

  const float* W  = dir ? Wb  : Wf;
  const float* bi = dir ? bb_ : bf_;

  const int lane = tid & 63;
  const int wid  = tid >> 6;
  const int ni   = wid & 1;     // batch half
  const int kh   = wid >> 1;    // K half
  const int hi   = lane >> 5;
  const int bcol = ni * 32 + (lane & 31);   // batch this lane owns (B-operand col)

  // ---- bias slice -> LDS (local col n: gate = n&3, unit u = n>>2) ----
  if (tid < 64) {
    biasl[tid] = bi[(tid & 3) * 512 + jsl * 16 + (tid >> 2)];
  }
  // ---- W slice -> LDS in A-fragment order: wfr[((kk*2+mi)*64+lane)*8+v] ----
  // value = W[k][gcol], k = kk*16 + (lane>>5)*8 + v, n = mi*32+(lane&31),
  // gcol = (n&3)*512 + jsl*16 + (n>>2).
  for (int i = tid; i < 48*2*64*8; i += 256) {
    const int ln = i & 63;
    const int r2 = i >> 6;
    const int v  = r2 & 7;
    const int m2 = (r2 >> 3) & 1;
    const int kk = r2 >> 4;
    const int k  = kk*16 + (ln >> 5)*8 + v;
    const int n  = m2*32 + (ln & 31);
    const int gcol = (n & 3)*512 + jsl*16 + (n >> 2);
    wfr[((size_t)(kk*2 + m2)*64 + ln)*8 + v] = (__bf16)W[(size_t)k*2048 + gcol];
  }
  __syncthreads();

  // bias only for the regs this wave finalizes: r = 8*kh + j, j=0..7
  float biasr[2][8];
  #pragma unroll
  for (int mi = 0; mi < 2; ++mi)
    #pragma unroll
    for (int j = 0; j < 8; ++j) {
      const int r = 8*kh + j;
      biasr[mi][j] = biasl[mi*32 + (r & 3) + 8*(r >> 2) + 4*hi];
    }

  float creg[4];   // cell state for the 4 (mi,sl) pairs this wave finalizes
  #pragma unroll
  for (int i = 0; i < 4; ++i) creg[i] = 0.0f;

  __hip_bfloat16* hb = hbuf + (size_t)dir * (2*NB*NH);   // [phase][64][512]
  unsigned int* myflag  = flags + (size_t)(dir*32 + jsl) * 16;
  unsigned int* pollptr = flags + (size_t)(dir*32 + (lane & 31)) * 16;

  f32x16 acc0, acc1;

  // ---- phase A for t=0: acc = bias-slot + x-part MFMAs (kh-split kk range) ----
  {
    #pragma unroll
    for (int r = 0; r < 16; ++r) { acc0[r] = 0.0f; acc1[r] = 0.0f; }
    #pragma unroll
    for (int j = 0; j < 8; ++j) { acc0[8*kh+j] = biasr[0][j]; acc1[8*kh+j] = biasr[1][j]; }
    const int trow = dir ? (NT - 1) : 0;
    const float* xbase = x + ((size_t)bcol * NT + trow) * ND;
    #pragma unroll 4
    for (int i = 0; i < 8; ++i) {
      const int kk = kh*8 + i;
      const int k  = kk*16 + hi*8;
      const float4 xa = *(const float4*)(xbase + k);
      const float4 xb = *(const float4*)(xbase + k + 4);
      bf16x8 bfr;
      bfr[0]=(__bf16)xa.x; bfr[1]=(__bf16)xa.y; bfr[2]=(__bf16)xa.z; bfr[3]=(__bf16)xa.w;
      bfr[4]=(__bf16)xb.x; bfr[5]=(__bf16)xb.y; bfr[6]=(__bf16)xb.z; bfr[7]=(__bf16)xb.w;
      const bf16x8 a0 = *(const bf16x8*)(wfr + ((size_t)(kk*2 + 0)*64 + lane)*8);
      const bf16x8 a1 = *(const bf16x8*)(wfr + ((size_t)(kk*2 + 1)*64 + lane)*8);
      acc0 = __builtin_amdgcn_mfma_f32_32x32x16_bf16(a0, bfr, acc0, 0, 0, 0);
      acc1 = __builtin_amdgcn_mfma_f32_32x32x16_bf16(a1, bfr, acc1, 0, 0, 0);
    }
  }

  #pragma unroll 1
  for (int t = 0; t < NT; ++t) {
    const __hip_bfloat16* hprev = hb + (size_t)(t & 1) * (NB*NH);
    __hip_bfloat16*       hnext = hb + (size_t)((t + 1) & 1) * (NB*NH);

    // ---- phase B: wait for all 32 WGs of this dir to have published h(t-1) ----
    if (t) {
      const unsigned int tgt = (unsigned int)t;
      while (!__all((int)(__hip_atomic_load(pollptr, __ATOMIC_RELAXED,
                                            __HIP_MEMORY_SCOPE_AGENT) >= tgt))) {}
      __builtin_amdgcn_fence(__ATOMIC_ACQUIRE, "agent");
    }

    // ---- phase C: h-part MFMAs (kh0: kk16..31, kh1: kk32..47) ----
    {
      const char* hrow = (const char*)(hprev + (size_t)bcol * NH);
      #pragma unroll 4
      for (int i = 0; i < 16; ++i) {
        const int kk = 16 + kh*16 + i;
        const int off = (kk*16 + hi*8 - ND) * 2;
        union { unsigned long long q[2]; bf16x8 v; } u;
        u.q[0] = agent_load_u64(hrow + off);
        u.q[1] = agent_load_u64(hrow + off + 8);
        const bf16x8 a0 = *(const bf16x8*)(wfr + ((size_t)(kk*2 + 0)*64 + lane)*8);
        const bf16x8 a1 = *(const bf16x8*)(wfr + ((size_t)(kk*2 + 1)*64 + lane)*8);
        acc0 = __builtin_amdgcn_mfma_f32_32x32x16_bf16(a0, u.v, acc0, 0, 0, 0);
        acc1 = __builtin_amdgcn_mfma_f32_32x32x16_bf16(a1, u.v, acc1, 0, 0, 0);
      }
    }

    // ---- symmetric half-exchange: write the half we don't finalize ----
    {
      const int r0w = 8*(1-kh);
      float* wslot = red + ((size_t)wid*64 + lane)*17;
      #pragma unroll
      for (int j = 0; j < 8; ++j) { wslot[j] = acc0[r0w+j]; wslot[8+j] = acc1[r0w+j]; }
    }
    __syncthreads();
    {
      const int r0 = 8*kh;
      const float* rslot = red + ((size_t)(wid ^ 2)*64 + lane)*17;
      #pragma unroll
      for (int j = 0; j < 8; ++j) { acc0[r0+j] += rslot[j]; acc1[r0+j] += rslot[8+j]; }

      // ---- elementwise: s = 2*kh + sl; regs 4s..4s+3 are f,i,o,g ----
      #pragma unroll
      for (int mi = 0; mi < 2; ++mi) {
        const f32x16 aa = mi ? acc1 : acc0;
        #pragma unroll
        for (int sl = 0; sl < 2; ++sl) {
          const int s  = 2*kh + sl;
          const float fg = fast_sigmoid(aa[4*s+0]);
          const float ig = fast_sigmoid(aa[4*s+1]);
          const float og = fast_sigmoid(aa[4*s+2]);
          const float gg = fast_tanh   (aa[4*s+3]);
          const int   p  = mi*2 + sl;
          const float cn = fg * creg[p] + ig * gg;
          creg[p] = cn;
          const float hv = og * fast_tanh(cn);
          hout[bcol*16 + (mi*8 + 2*s + hi)] = __float2bfloat16(hv);
        }
      }
    }
    __syncthreads();

    // ---- publish this WG's h slice (2 KB, coalesced u64 per thread) ----
    {
      const unsigned long long vv = ((const unsigned long long*)hout)[tid];
      agent_store_u64(hnext + (size_t)(tid >> 2)*NH + jsl*16 + (tid & 3)*4, vv);
    }

    // ---- phase A for t+1 (x-part, flag-independent) hides store latency ----
    if (t + 1 < NT) {
      #pragma unroll
      for (int r = 0; r < 16; ++r) { acc0[r] = 0.0f; acc1[r] = 0.0f; }
      #pragma unroll
      for (int j = 0; j < 8; ++j) { acc0[8*kh+j] = biasr[0][j]; acc1[8*kh+j] = biasr[1][j]; }
      const int trow = dir ? (NT - 2 - t) : (t + 1);
      const float* xbase = x + ((size_t)bcol * NT + trow) * ND;
      #pragma unroll 4
      for (int i = 0; i < 8; ++i) {
        const int kk = kh*8 + i;
        const int k  = kk*16 + hi*8;
        const float4 xa = *(const float4*)(xbase + k);
        const float4 xb = *(const float4*)(xbase + k + 4);
        bf16x8 bfr;
        bfr[0]=(__bf16)xa.x; bfr[1]=(__bf16)xa.y; bfr[2]=(__bf16)xa.z; bfr[3]=(__bf16)xa.w;
        bfr[4]=(__bf16)xb.x; bfr[5]=(__bf16)xb.y; bfr[6]=(__bf16)xb.z; bfr[7]=(__bf16)xb.w;
        const bf16x8 a0 = *(const bf16x8*)(wfr + ((size_t)(kk*2 + 0)*64 + lane)*8);
        const bf16x8 a1 = *(const bf16x8*)(wfr + ((size_t)(kk*2 + 1)*64 + lane)*8);
        acc0 = __builtin_amdgcn_mfma_f32_32x32x16_bf16(a0, bfr, acc0, 0, 0, 0);
        acc1 = __builtin_amdgcn_mfma_f32_32x32x16_bf16(a1, bfr, acc1, 0, 0, 0);
      }
    }

    // ---- make publish visible, then raise our flag ----
    __builtin_amdgcn_fence(__ATOMIC_RELEASE, "agent");
    __syncthreads();
    if (tid == 0) {
      __hip_atomic_store(myflag, (unsigned int)(t + 1), __ATOMIC_RELAXED,
                         __HIP_MEMORY_SCOPE_AGENT);
    }
  }
}

// out[b][o] = [h_fwd | h_bwd] @ W_fc + b_fc   (final h lives in phase 0)
__global__ __launch_bounds__(128) void fc_out(
    const __hip_bfloat16* __restrict__ hbuf, const float* __restrict__ Wfc,
    const float* __restrict__ bfc, float* __restrict__ out)
{
  __shared__ float hrow[2*NH];
  const int b = blockIdx.x, o = threadIdx.x;
  const __hip_bfloat16* hf  = hbuf + (size_t)b*NH;                    // dir0 phase0
  const __hip_bfloat16* hb2 = hbuf + (size_t)2*NB*NH + (size_t)b*NH;  // dir1 phase0
  for (int i = o; i < NH; i += 128) {
    hrow[i]      = __bfloat162float(hf[i]);
    hrow[NH + i] = __bfloat162float(hb2[i]);
  }
  __syncthreads();
  float acc = bfc[o];
  for (int k = 0; k < 2*NH; ++k)
    acc = fmaf(hrow[k], Wfc[(size_t)k*128 + o], acc);
  out[b*128 + o] = acc;
}

extern "C" void kernel_launch(void* const* d_in, const int* in_sizes, int n_in,
                              void* d_out, int out_size, void* d_ws, size_t ws_size,
                              hipStream_t stream) {
  (void)in_sizes; (void)n_in; (void)out_size; (void)ws_size;
  const float* x   = (const float*)d_in[0];
  const float* Wf  = (const float*)d_in[1];
  const float* bf_ = (const float*)d_in[2];
  const float* Wb  = (const float*)d_in[3];
  const float* bb_ = (const float*)d_in[4];
  const float* Wfc = (const float*)d_in[5];
  const float* bfc = (const float*)d_in[6];
  float* out = (float*)d_out;

  // ws: hbuf [2 dir][2 phase][64][512] bf16 = 262144 B; flags [2][32][16] u32 = 4096 B
  __hip_bfloat16* hbuf  = (__hip_bfloat16*)d_ws;
  unsigned int*   flags = (unsigned int*)((char*)d_ws + 2*2*NB*NH*2);

  hipMemsetAsync(d_ws, 0, 2*2*NB*NH*2 + 2*32*16*4, stream);  // h0=c0=0, flags=0

  hipFuncSetAttribute((const void*)bilstm_persist,
                      hipFuncAttributeMaxDynamicSharedMemorySize, LDS_TOTAL);

  bilstm_persist<<<dim3(64), dim3(256), LDS_TOTAL, stream>>>(x, Wf, bf_, Wb, bb_, hbuf, flags);
  fc_out<<<dim3(NB), dim3(128), 0, stream>>>(hbuf, Wfc, bfc, out);
}

// Round 5
// 12199.097 us; speedup vs baseline: 1.2681x; 1.2681x over previous
//
#include <hip/hip_runtime.h>
#include <hip/hip_bf16.h>
#include <stdint.h>

typedef __bf16  bf16x8 __attribute__((ext_vector_type(8)));
typedef float   f32x16 __attribute__((ext_vector_type(16)));

#define NB   64
#define NT   1024
#define ND   256
#define NH   512
#define NWGD 32

// LDS layout (bytes)
#define LDS_WFR   0                        // 48*2*64*8 bf16 = 98304
#define LDS_RED   98304                    // 4*64*17 f32   = 17408
#define LDS_HOUT  (98304+17408)            // 64*16 bf16    = 2048
#define LDS_BIAS  (98304+17408+2048)       // 64 f32        = 256
#define LDS_TOTAL (98304+17408+2048+256)   // 118016 -> 1 WG/CU

// ws layout (bytes)
#define HB_BYTES   (2*2*NB*NH*2)           // 262144
#define FLAGS_OFF  HB_BYTES                // [2][32][16] u32 = 4096
#define WS_USED    (FLAGS_OFF + 4096)

static __device__ __forceinline__ unsigned long long agent_load_u64(const void* p) {
  return __hip_atomic_load((const unsigned long long*)p, __ATOMIC_RELAXED,
                           __HIP_MEMORY_SCOPE_AGENT);
}
static __device__ __forceinline__ void agent_store_u64(void* p, unsigned long long v) {
  __hip_atomic_store((unsigned long long*)p, v, __ATOMIC_RELAXED,
                     __HIP_MEMORY_SCOPE_AGENT);
}
static __device__ __forceinline__ float fast_sigmoid(float v) {
  return __builtin_amdgcn_rcpf(1.0f + __expf(-v));
}
static __device__ __forceinline__ float fast_tanh(float v) {
  return 1.0f - 2.0f * __builtin_amdgcn_rcpf(1.0f + __expf(2.0f * v));
}

// Persistent bidirectional LSTM. 64 WGs: dir = bid>>5, jsl = bid&31 (16 hidden
// units -> 64 gate cols, gate-interleaved n=4u+g). Per step per WG:
// G^T[64][64b] = Wslice^T[64][768] @ act^T[768][64], mfma_f32_32x32x16_bf16.
// Waves (ni=batch-half, kh=K-half). Phase A (x part, kh0 kk0..7 / kh1 kk8..15)
// runs between publish and flag-raise (hides store drain); phase C (h part,
// kh0 kk16..31 / kh1 kk32..47) after the flag poll, with ALL 32 agent loads
// batched into registers before any MFMA (single waitcnt -> one LIC RT).
// Sync: per-WG flag word, wave0 __all-poll, no fences, no contended RMW.
// Plain HIP only — no inline asm (R2/R3 asm variants never survived the
// harness).
__global__ __launch_bounds__(256, 1) void bilstm_persist(
    const float* __restrict__ x,
    const float* __restrict__ Wf, const float* __restrict__ bf_,
    const float* __restrict__ Wb, const float* __restrict__ bb_,
    __hip_bfloat16* __restrict__ hbuf, unsigned int* __restrict__ flags)
{
  extern __shared__ char smem[];
  __bf16*         wfr   = (__bf16*)(smem + LDS_WFR);
  float*          red   = (float*) (smem + LDS_RED);
  __hip_bfloat16* hout  = (__hip_bfloat16*)(smem + LDS_HOUT);
  float*          biasl = (float*) (smem + LDS_BIAS);

  const int tid = threadIdx.x;
  const int bid = blockIdx.x;
  const int dir = bid >> 5;
  const int jsl = bid & 31;

  const float* W  = dir ? Wb  : Wf;
  const float* bi = dir ? bb_ : bf_;

  const int lane = tid & 63;
  const int wid  = tid >> 6;
  const int kh   = wid >> 1;    // K half
  const int hi   = lane >> 5;
  const int bcol = (wid & 1) * 32 + (lane & 31);   // batch this lane owns

  // ---- bias slice -> LDS (local col n: gate = n&3, unit u = n>>2) ----
  if (tid < 64) {
    biasl[tid] = bi[(tid & 3) * 512 + jsl * 16 + (tid >> 2)];
  }
  // ---- W slice -> LDS in A-fragment order: wfr[((kk*2+mi)*64+lane)*8+v] ----
  // value = W[k][gcol], k = kk*16 + (lane>>5)*8 + v, n = mi*32+(lane&31),
  // gcol = (n&3)*512 + jsl*16 + (n>>2).
  for (int i = tid; i < 48*2*64*8; i += 256) {
    const int ln = i & 63;
    const int r2 = i >> 6;
    const int v  = r2 & 7;
    const int m2 = (r2 >> 3) & 1;
    const int kk = r2 >> 4;
    const int k  = kk*16 + (ln >> 5)*8 + v;
    const int n  = m2*32 + (ln & 31);
    const int gcol = (n & 3)*512 + jsl*16 + (n >> 2);
    wfr[((size_t)(kk*2 + m2)*64 + ln)*8 + v] = (__bf16)W[(size_t)k*2048 + gcol];
  }
  __syncthreads();

  // bias only for the regs this wave finalizes: r = 8*kh + j
  float biasr[2][8];
  #pragma unroll
  for (int mi = 0; mi < 2; ++mi)
    #pragma unroll
    for (int j = 0; j < 8; ++j) {
      const int r = 8*kh + j;
      biasr[mi][j] = biasl[mi*32 + (r & 3) + 8*(r >> 2) + 4*hi];
    }

  float creg[4];   // cell state for the 4 (mi,sl) pairs this wave finalizes
  #pragma unroll
  for (int i = 0; i < 4; ++i) creg[i] = 0.0f;

  __hip_bfloat16* hb = hbuf + (size_t)dir * (2*NB*NH);   // [phase][64][512]
  unsigned int* myflag  = flags + (size_t)(dir*32 + jsl) * 16;
  unsigned int* pollptr = flags + (size_t)(dir*32 + (lane & 31)) * 16;

  f32x16 acc0, acc1;

  // ---- phase A for t=0 (x part, kh-split) ----
  {
    #pragma unroll
    for (int r = 0; r < 16; ++r) { acc0[r] = 0.0f; acc1[r] = 0.0f; }
    #pragma unroll
    for (int j = 0; j < 8; ++j) { acc0[8*kh+j] = biasr[0][j]; acc1[8*kh+j] = biasr[1][j]; }
    const int trow = dir ? (NT - 1) : 0;
    const float* xbase = x + ((size_t)bcol * NT + trow) * ND;
    #pragma unroll 4
    for (int i = 0; i < 8; ++i) {
      const int kk = kh*8 + i;
      const int k  = kk*16 + hi*8;
      const float4 xa = *(const float4*)(xbase + k);
      const float4 xb = *(const float4*)(xbase + k + 4);
      bf16x8 bfr;
      bfr[0]=(__bf16)xa.x; bfr[1]=(__bf16)xa.y; bfr[2]=(__bf16)xa.z; bfr[3]=(__bf16)xa.w;
      bfr[4]=(__bf16)xb.x; bfr[5]=(__bf16)xb.y; bfr[6]=(__bf16)xb.z; bfr[7]=(__bf16)xb.w;
      const bf16x8 a0 = *(const bf16x8*)(wfr + ((size_t)(kk*2 + 0)*64 + lane)*8);
      const bf16x8 a1 = *(const bf16x8*)(wfr + ((size_t)(kk*2 + 1)*64 + lane)*8);
      acc0 = __builtin_amdgcn_mfma_f32_32x32x16_bf16(a0, bfr, acc0, 0, 0, 0);
      acc1 = __builtin_amdgcn_mfma_f32_32x32x16_bf16(a1, bfr, acc1, 0, 0, 0);
    }
  }

  #pragma unroll 1
  for (int t = 0; t < NT; ++t) {
    const __hip_bfloat16* hprev = hb + (size_t)(t & 1) * (NB*NH);
    __hip_bfloat16*       hnext = hb + (size_t)((t + 1) & 1) * (NB*NH);

    // ---- phase B: wave0 polls the 32 per-WG flags of this dir ----
    if (t) {
      if (wid == 0) {
        const unsigned int tgt = (unsigned int)t;
        unsigned int f;
        do {
          f = __hip_atomic_load(pollptr, __ATOMIC_RELAXED,
                                __HIP_MEMORY_SCOPE_AGENT);
          if (__all((int)(f >= tgt))) break;
          __builtin_amdgcn_s_sleep(2);
        } while (1);
      }
      __syncthreads();
    }

    // ---- phase C: h-part. Batch ALL 32 agent loads, then MFMAs. ----
    {
      const char* hrow = (const char*)(hprev + (size_t)bcol * NH);
      unsigned long long q[32];
      #pragma unroll
      for (int i = 0; i < 16; ++i) {
        const int kk  = 16 + kh*16 + i;
        const int off = (kk*16 + hi*8 - ND) * 2;
        q[2*i]   = agent_load_u64(hrow + off);
        q[2*i+1] = agent_load_u64(hrow + off + 8);
      }
      #pragma unroll
      for (int i = 0; i < 16; ++i) {
        union { unsigned long long qq[2]; bf16x8 v; } u;
        u.qq[0] = q[2*i]; u.qq[1] = q[2*i+1];
        const int kk = 16 + kh*16 + i;
        const bf16x8 a0 = *(const bf16x8*)(wfr + ((size_t)(kk*2 + 0)*64 + lane)*8);
        const bf16x8 a1 = *(const bf16x8*)(wfr + ((size_t)(kk*2 + 1)*64 + lane)*8);
        acc0 = __builtin_amdgcn_mfma_f32_32x32x16_bf16(a0, u.v, acc0, 0, 0, 0);
        acc1 = __builtin_amdgcn_mfma_f32_32x32x16_bf16(a1, u.v, acc1, 0, 0, 0);
      }
    }

    // ---- symmetric half-exchange + elementwise ----
    {
      const int r0w = 8*(1-kh);
      float* wslot = red + ((size_t)wid*64 + lane)*17;
      #pragma unroll
      for (int j = 0; j < 8; ++j) { wslot[j] = acc0[r0w+j]; wslot[8+j] = acc1[r0w+j]; }
    }
    __syncthreads();
    {
      const int r0 = 8*kh;
      const float* rslot = red + ((size_t)(wid ^ 2)*64 + lane)*17;
      #pragma unroll
      for (int j = 0; j < 8; ++j) { acc0[r0+j] += rslot[j]; acc1[r0+j] += rslot[8+j]; }

      #pragma unroll
      for (int mi = 0; mi < 2; ++mi) {
        const f32x16 aa = mi ? acc1 : acc0;
        #pragma unroll
        for (int sl = 0; sl < 2; ++sl) {
          const int s  = 2*kh + sl;
          const float fg = fast_sigmoid(aa[4*s+0]);
          const float ig = fast_sigmoid(aa[4*s+1]);
          const float og = fast_sigmoid(aa[4*s+2]);
          const float gg = fast_tanh   (aa[4*s+3]);
          const int   p  = mi*2 + sl;
          const float cn = fg * creg[p] + ig * gg;
          creg[p] = cn;
          const float hv = og * fast_tanh(cn);
          hout[bcol*16 + (mi*8 + 2*s + hi)] = __float2bfloat16(hv);
        }
      }
    }
    __syncthreads();

    // ---- publish this WG's h slice (2 KB, coalesced u64 per thread) ----
    {
      const unsigned long long vv = ((const unsigned long long*)hout)[tid];
      agent_store_u64(hnext + (size_t)(tid >> 2)*NH + jsl*16 + (tid & 3)*4, vv);
    }

    // ---- phase A for t+1 (flag-independent; hides publish drain) ----
    if (t + 1 < NT) {
      #pragma unroll
      for (int r = 0; r < 16; ++r) { acc0[r] = 0.0f; acc1[r] = 0.0f; }
      #pragma unroll
      for (int j = 0; j < 8; ++j) { acc0[8*kh+j] = biasr[0][j]; acc1[8*kh+j] = biasr[1][j]; }
      const int trow = dir ? (NT - 2 - t) : (t + 1);
      const float* xbase = x + ((size_t)bcol * NT + trow) * ND;
      #pragma unroll 4
      for (int i = 0; i < 8; ++i) {
        const int kk = kh*8 + i;
        const int k  = kk*16 + hi*8;
        const float4 xa = *(const float4*)(xbase + k);
        const float4 xb = *(const float4*)(xbase + k + 4);
        bf16x8 bfr;
        bfr[0]=(__bf16)xa.x; bfr[1]=(__bf16)xa.y; bfr[2]=(__bf16)xa.z; bfr[3]=(__bf16)xa.w;
        bfr[4]=(__bf16)xb.x; bfr[5]=(__bf16)xb.y; bfr[6]=(__bf16)xb.z; bfr[7]=(__bf16)xb.w;
        const bf16x8 a0 = *(const bf16x8*)(wfr + ((size_t)(kk*2 + 0)*64 + lane)*8);
        const bf16x8 a1 = *(const bf16x8*)(wfr + ((size_t)(kk*2 + 1)*64 + lane)*8);
        acc0 = __builtin_amdgcn_mfma_f32_32x32x16_bf16(a0, bfr, acc0, 0, 0, 0);
        acc1 = __builtin_amdgcn_mfma_f32_32x32x16_bf16(a1, bfr, acc1, 0, 0, 0);
      }
    }

    // ---- __syncthreads drains each wave's vmcnt (publish acked), flag ----
    __syncthreads();
    if (tid == 0) {
      __hip_atomic_store(myflag, (unsigned int)(t + 1), __ATOMIC_RELAXED,
                         __HIP_MEMORY_SCOPE_AGENT);
    }
  }
}

// out[b][o] = [h_fwd | h_bwd] @ W_fc + b_fc   (final h lives in phase 0)
__global__ __launch_bounds__(128) void fc_out(
    const __hip_bfloat16* __restrict__ hbuf, const float* __restrict__ Wfc,
    const float* __restrict__ bfc, float* __restrict__ out)
{
  __shared__ float hrow[2*NH];
  const int b = blockIdx.x, o = threadIdx.x;
  const __hip_bfloat16* hf  = hbuf + (size_t)b*NH;                    // dir0 phase0
  const __hip_bfloat16* hb2 = hbuf + (size_t)2*NB*NH + (size_t)b*NH;  // dir1 phase0
  for (int i = o; i < NH; i += 128) {
    hrow[i]      = __bfloat162float(hf[i]);
    hrow[NH + i] = __bfloat162float(hb2[i]);
  }
  __syncthreads();
  float acc = bfc[o];
  for (int k = 0; k < 2*NH; ++k)
    acc = fmaf(hrow[k], Wfc[(size_t)k*128 + o], acc);
  out[b*128 + o] = acc;
}

extern "C" void kernel_launch(void* const* d_in, const int* in_sizes, int n_in,
                              void* d_out, int out_size, void* d_ws, size_t ws_size,
                              hipStream_t stream) {
  (void)in_sizes; (void)n_in; (void)out_size; (void)ws_size;
  const float* x   = (const float*)d_in[0];
  const float* Wf  = (const float*)d_in[1];
  const float* bf_ = (const float*)d_in[2];
  const float* Wb  = (const float*)d_in[3];
  const float* bb_ = (const float*)d_in[4];
  const float* Wfc = (const float*)d_in[5];
  const float* bfc = (const float*)d_in[6];
  float* out = (float*)d_out;

  __hip_bfloat16* hbuf  = (__hip_bfloat16*)d_ws;
  unsigned int*   flags = (unsigned int*)((char*)d_ws + FLAGS_OFF);

  hipMemsetAsync(d_ws, 0, WS_USED, stream);  // h0=c0=0, flags=0

  hipFuncSetAttribute((const void*)bilstm_persist,
                      hipFuncAttributeMaxDynamicSharedMemorySize, LDS_TOTAL);

  bilstm_persist<<<dim3(64), dim3(256), LDS_TOTAL, stream>>>(
      x, Wf, bf_, Wb, bb_, hbuf, flags);
  fc_out<<<dim3(NB), dim3(128), 0, stream>>>(hbuf, Wfc, bfc, out);
}